// Round 1
// baseline (114.037 us; speedup 1.0000x reference)
//
#include <hip/hip_runtime.h>
#include <math.h>

#define D 256
#define N 16
#define R 16

__device__ __forceinline__ float silu_f(float x) {
    return x / (1.0f + expf(-x));
}

__device__ __forceinline__ float softplus_f(float x) {
    // stable: max(x,0) + log1p(exp(-|x|))
    return fmaxf(x, 0.0f) + log1pf(expf(-fabsf(x)));
}

// 256 threads = 4 waves. Pre-barrier protects s_red reuse across calls.
__device__ __forceinline__ float block_reduce_sum(float v, float* s_red) {
    #pragma unroll
    for (int off = 32; off >= 1; off >>= 1)
        v += __shfl_down(v, off, 64);
    const int wave = threadIdx.x >> 6;
    const int lane = threadIdx.x & 63;
    __syncthreads();                 // protect previous reads of s_red
    if (lane == 0) s_red[wave] = v;
    __syncthreads();
    return s_red[0] + s_red[1] + s_red[2] + s_red[3];
}

__global__ __launch_bounds__(256) void mamba_collapsed_kernel(
    const float* __restrict__ x1_in, const float* __restrict__ x2_in,
    const float* __restrict__ norm_w, const float* __restrict__ conv_w,
    const float* __restrict__ conv_b, const float* __restrict__ in_w,
    const float* __restrict__ xproj_w, const float* __restrict__ dt_w,
    const float* __restrict__ dt_b, const float* __restrict__ out_w,
    const float* __restrict__ A_log, const float* __restrict__ Dp,
    const int* __restrict__ l_ptr, float* __restrict__ out)
{
    const int b = blockIdx.x;
    const int j = threadIdx.x;   // channel index, 0..255
    const int l = *l_ptr;

    __shared__ float s_n1[D];
    __shared__ float s_n2[D];
    __shared__ float s_x2s[4][D];
    __shared__ float s_xdbl[4][48];   // [tc][delta(16) | B(16) | C(16)]
    __shared__ float s_y[D];
    __shared__ float s_red[4];

    // ---- 1. rmsnorm(x_1), rmsnorm(x_2) ----
    const float v1 = x1_in[b * D + j];
    const float v2 = x2_in[b * D + j];
    const float ss1 = block_reduce_sum(v1 * v1, s_red);
    const float ss2 = block_reduce_sum(v2 * v2, s_red);
    const float wn = norm_w[j];
    s_n1[j] = v1 * rsqrtf(ss1 * (1.0f / D) + 1e-5f) * wn;
    s_n2[j] = v2 * rsqrtf(ss2 * (1.0f / D) + 1e-5f) * wn;
    __syncthreads();

    // ---- 2. in_w matvec: x1c, res1 (from n1) and x2c (from n2) ----
    // thread j owns output channel j; rows of in_w are contiguous.
    const float* __restrict__ wrow_a = in_w + (size_t)j * D;        // row j
    const float* __restrict__ wrow_b = in_w + (size_t)(j + D) * D;  // row j+256
    float x1c = 0.0f, res1 = 0.0f, x2c = 0.0f;
    #pragma unroll 4
    for (int i = 0; i < D; i += 4) {
        const float4 wa = *(const float4*)(wrow_a + i);
        const float4 wb = *(const float4*)(wrow_b + i);
        const float n1x = s_n1[i], n1y = s_n1[i+1], n1z = s_n1[i+2], n1w = s_n1[i+3];
        const float n2x = s_n2[i], n2y = s_n2[i+1], n2z = s_n2[i+2], n2w = s_n2[i+3];
        x1c  += wa.x*n1x + wa.y*n1y + wa.z*n1z + wa.w*n1w;
        res1 += wb.x*n1x + wb.y*n1y + wb.z*n1z + wb.w*n1w;
        x2c  += wa.x*n2x + wa.y*n2y + wa.z*n2z + wa.w*n2w;
    }

    // ---- 3. depthwise conv on constant sequence -> 4 time-classes + silu ----
    const float cw0 = conv_w[j*4 + 0], cw1 = conv_w[j*4 + 1],
                cw2 = conv_w[j*4 + 2], cw3 = conv_w[j*4 + 3];
    const float cb = conv_b[j];
    float ksum[4];
    ksum[0] = cw3;                      // t = 0
    ksum[1] = cw2 + cw3;                // t = 1
    ksum[2] = cw1 + cw2 + cw3;          // t = 2
    ksum[3] = cw0 + cw1 + cw2 + cw3;    // t >= 3
    float x1s[4];
    #pragma unroll
    for (int tc = 0; tc < 4; ++tc) {
        x1s[tc] = silu_f(ksum[tc] * x1c + cb);
        s_x2s[tc][j] = silu_f(ksum[tc] * x2c + cb);
    }
    __syncthreads();

    // ---- 4. xproj: xdbl[tc][o] = dot(x2s[tc], xproj_w[o]) for 4*48 outputs ----
    if (j < 192) {
        const int tc = j / 48;
        const int o  = j % 48;
        const float* __restrict__ prow = xproj_w + (size_t)o * D;
        const float* __restrict__ xs   = s_x2s[tc];
        float acc = 0.0f;
        #pragma unroll 4
        for (int i = 0; i < D; i += 4) {
            const float4 p = *(const float4*)(prow + i);
            acc += p.x*xs[i] + p.y*xs[i+1] + p.z*xs[i+2] + p.w*xs[i+3];
        }
        s_xdbl[tc][o] = acc;
    }
    __syncthreads();

    // ---- 5. delta[tc][j] = softplus(dot(xdbl[tc][0:16], dt_w[j]) + dt_b[j]) ----
    const float* __restrict__ dtrow = dt_w + (size_t)j * R;
    float dtr[R];
    #pragma unroll
    for (int q = 0; q < R; ++q) dtr[q] = dtrow[q];
    const float dtb = dt_b[j];
    float delta[4];
    #pragma unroll
    for (int tc = 0; tc < 4; ++tc) {
        float acc = 0.0f;
        #pragma unroll
        for (int q = 0; q < R; ++q) acc += s_xdbl[tc][q] * dtr[q];
        delta[tc] = softplus_f(acc + dtb);
    }

    // ---- 6. A[j][n] = -exp(A_log[j][n]) ----
    const float* __restrict__ arow = A_log + (size_t)j * N;
    float Aa[N];
    #pragma unroll
    for (int n = 0; n < N; ++n) Aa[n] = -expf(arow[n]);

    // ---- 7. selective-scan: 3 explicit steps + closed-form geometric tail ----
    float h[N];
    #pragma unroll
    for (int n = 0; n < N; ++n) h[n] = 0.0f;

    const int nexp = (l < 3) ? l : 3;
    for (int t = 0; t < nexp; ++t) {
        const float dl = delta[t];
        const float du = dl * x1s[t];
        #pragma unroll
        for (int n = 0; n < N; ++n) {
            const float dA = expf(dl * Aa[n]);
            h[n] = dA * h[n] + du * s_xdbl[t][16 + n];
        }
    }
    if (l > 3) {
        const float dl = delta[3];
        const float du = dl * x1s[3];
        const float steps = (float)(l - 3);
        #pragma unroll
        for (int n = 0; n < N; ++n) {
            const float z   = dl * Aa[n];          // z < 0
            const float em1 = expm1f(z);
            const float emN = expm1f(steps * z);
            // (1 - dA^steps)/(1 - dA), stable near z = 0
            const float ratio = (em1 != 0.0f) ? (emN / em1) : steps;
            const float p = emN + 1.0f;            // dA^steps
            h[n] = p * h[n] + du * s_xdbl[3][16 + n] * ratio;
        }
    }

    // ---- y_{l-1} = h . C_{l-1}; + x1s*D; * silu(res1) ----
    const int fc = ((l - 1) < 3) ? (l - 1) : 3;   // time-class of final step
    float y = 0.0f;
    #pragma unroll
    for (int n = 0; n < N; ++n) y += h[n] * s_xdbl[fc][32 + n];
    y += x1s[fc] * Dp[j];
    y *= silu_f(res1);
    s_y[j] = y;
    __syncthreads();

    // ---- 8. out_w matvec + final rmsnorm ----
    const float* __restrict__ orow = out_w + (size_t)j * D;
    float z = 0.0f;
    #pragma unroll 4
    for (int i = 0; i < D; i += 4) {
        const float4 ow = *(const float4*)(orow + i);
        z += ow.x*s_y[i] + ow.y*s_y[i+1] + ow.z*s_y[i+2] + ow.w*s_y[i+3];
    }
    const float ssz = block_reduce_sum(z * z, s_red);
    out[b * D + j] = z * rsqrtf(ssz * (1.0f / D) + 1e-5f) * norm_w[j];
}

extern "C" void kernel_launch(void* const* d_in, const int* in_sizes, int n_in,
                              void* d_out, int out_size, void* d_ws, size_t ws_size,
                              hipStream_t stream) {
    const float* x1      = (const float*)d_in[0];
    const float* x2      = (const float*)d_in[1];
    const float* norm_w  = (const float*)d_in[2];
    const float* conv_w  = (const float*)d_in[3];
    const float* conv_b  = (const float*)d_in[4];
    const float* in_w    = (const float*)d_in[5];
    const float* xproj_w = (const float*)d_in[6];
    const float* dt_w    = (const float*)d_in[7];
    const float* dt_b    = (const float*)d_in[8];
    const float* out_w   = (const float*)d_in[9];
    const float* A_log   = (const float*)d_in[10];
    const float* Dp      = (const float*)d_in[11];
    const int*   l_ptr   = (const int*)d_in[12];
    float* out = (float*)d_out;

    const int batch = in_sizes[0] / D;   // 64
    mamba_collapsed_kernel<<<dim3(batch), dim3(D), 0, stream>>>(
        x1, x2, norm_w, conv_w, conv_b, in_w, xproj_w, dt_w, dt_b,
        out_w, A_log, Dp, l_ptr, out);
}

// Round 2
// 96.953 us; speedup vs baseline: 1.1762x; 1.1762x over previous
//
#include <hip/hip_runtime.h>
#include <math.h>

#define D 256
#define N 16
#define R 16

// workspace float offsets (total 64*256*4 floats = 256 KB)
#define WS_X1C  0
#define WS_RES1 16384
#define WS_X2C  32768
#define WS_Y    49152

__device__ __forceinline__ float silu_f(float x) { return x / (1.0f + expf(-x)); }
__device__ __forceinline__ float softplus_f(float x) {
    return fmaxf(x, 0.0f) + log1pf(expf(-fabsf(x)));
}

// ---------------- K1: rmsnorm + in_w matvec ----------------
// grid: (64 batches * 768 dots)/64 = 768 blocks, 256 threads.
// Block handles dots g = blk*64 .. +63; g = b*768 + o (regions don't straddle).
//   o in [0,256):   x1c  = n1 . in_w[o]
//   o in [256,512): res1 = n1 . in_w[o]
//   o in [512,768): x2c  = n2 . in_w[o-512]
__global__ __launch_bounds__(256) void k_inw(
    const float* __restrict__ x1_in, const float* __restrict__ x2_in,
    const float* __restrict__ norm_w, const float* __restrict__ in_w,
    float* __restrict__ ws)
{
    __shared__ float s_n[D];
    __shared__ float s_red[4];
    const int t  = threadIdx.x;
    const int g0 = blockIdx.x * 64;
    const int b  = g0 / 768;
    const int o0 = g0 % 768;
    const bool use2 = (o0 >= 512);

    // phase 0: rmsnorm the one input row this block needs, into LDS
    const float* __restrict__ xrow = (use2 ? x2_in : x1_in) + (size_t)b * D;
    const float v = xrow[t];
    float p = v * v;
    #pragma unroll
    for (int off = 32; off >= 1; off >>= 1) p += __shfl_down(p, off, 64);
    if ((t & 63) == 0) s_red[t >> 6] = p;
    __syncthreads();
    const float ss = s_red[0] + s_red[1] + s_red[2] + s_red[3];
    s_n[t] = v * rsqrtf(ss * (1.0f / D) + 1e-5f) * norm_w[t];
    __syncthreads();

    // phase 1: 64 dots, 4 threads/dot, interleaved quarters (bank-conflict-free)
    const int o   = o0 + (t >> 2);
    const int q   = t & 3;
    const int row = (o >= 512) ? (o - 512) : o;
    const float* __restrict__ wr = in_w + (size_t)row * D;
    float acc = 0.0f;
    #pragma unroll
    for (int k = 0; k < 16; ++k) {
        const int e = q * 4 + 16 * k;
        const float4 w4 = *(const float4*)(wr + e);
        const float4 n4 = *(const float4*)(s_n + e);
        acc += w4.x*n4.x + w4.y*n4.y + w4.z*n4.z + w4.w*n4.w;
    }
    acc += __shfl_xor(acc, 1, 64);
    acc += __shfl_xor(acc, 2, 64);
    if (q == 0) {
        const int jj = o & 255;
        float* dst = (o < 256) ? (ws + WS_X1C)
                   : (o < 512) ? (ws + WS_RES1)
                               : (ws + WS_X2C);
        dst[b * D + jj] = acc;
    }
}

// ---------------- K2: conv+silu, xproj, dt, scan, y ----------------
// grid: 64 blocks (one per batch), 1024 threads.
__global__ __launch_bounds__(1024) void k_scan(
    const float* __restrict__ conv_w, const float* __restrict__ conv_b,
    const float* __restrict__ xproj_w, const float* __restrict__ dt_w,
    const float* __restrict__ dt_b, const float* __restrict__ A_log,
    const float* __restrict__ Dp, const int* __restrict__ l_ptr,
    float* __restrict__ ws)
{
    __shared__ float s_x2s[4][D];
    __shared__ float s_xdbl[4][48];   // [tc][delta(16)|B(16)|C(16)]
    const int b = blockIdx.x;
    const int t = threadIdx.x;
    const int l = *l_ptr;

    float x1s[4];
    if (t < D) {
        const float x1c = ws[WS_X1C + b * D + t];
        const float x2c = ws[WS_X2C + b * D + t];
        const float4 cw = *(const float4*)(conv_w + 4 * t);
        const float cb  = conv_b[t];
        float ksum[4];
        ksum[0] = cw.w;
        ksum[1] = cw.z + cw.w;
        ksum[2] = cw.y + cw.z + cw.w;
        ksum[3] = cw.x + cw.y + cw.z + cw.w;
        #pragma unroll
        for (int tc = 0; tc < 4; ++tc) {
            x1s[tc] = silu_f(ksum[tc] * x1c + cb);
            s_x2s[tc][t] = silu_f(ksum[tc] * x2c + cb);
        }
    }
    __syncthreads();

    // xproj: 4*48 = 192 dots of 256, 4 threads/dot -> 768 threads
    if (t < 768) {
        const int dotid = t >> 2;
        const int q     = t & 3;
        const int tc    = dotid / 48;
        const int o     = dotid % 48;
        const float* __restrict__ pr = xproj_w + (size_t)o * D;
        const float* __restrict__ xs = s_x2s[tc];
        float acc = 0.0f;
        #pragma unroll
        for (int k = 0; k < 16; ++k) {
            const int e = q * 4 + 16 * k;
            const float4 p4 = *(const float4*)(pr + e);
            const float4 x4 = *(const float4*)(xs + e);
            acc += p4.x*x4.x + p4.y*x4.y + p4.z*x4.z + p4.w*x4.w;
        }
        acc += __shfl_xor(acc, 1, 64);
        acc += __shfl_xor(acc, 2, 64);
        if (q == 0) s_xdbl[tc][o] = acc;
    }
    __syncthreads();

    if (t < D) {
        const int j = t;
        // delta[tc] = softplus(xdbl[tc][0:16] . dt_w[j] + dt_b[j])
        const float* __restrict__ dtrow = dt_w + (size_t)j * R;
        float dtr[R];
        #pragma unroll
        for (int qq = 0; qq < R; ++qq) dtr[qq] = dtrow[qq];
        const float dtb = dt_b[j];
        float delta[4];
        #pragma unroll
        for (int tc = 0; tc < 4; ++tc) {
            float acc = 0.0f;
            #pragma unroll
            for (int qq = 0; qq < R; ++qq) acc += s_xdbl[tc][qq] * dtr[qq];
            delta[tc] = softplus_f(acc + dtb);
        }
        // A row
        const float* __restrict__ arow = A_log + (size_t)j * N;
        float Aa[N];
        #pragma unroll
        for (int n = 0; n < N; ++n) Aa[n] = -expf(arow[n]);
        // scan: 3 explicit steps + closed-form geometric tail
        float h[N];
        #pragma unroll
        for (int n = 0; n < N; ++n) h[n] = 0.0f;
        const int nexp = (l < 3) ? l : 3;
        for (int tt = 0; tt < nexp; ++tt) {
            const float dl = delta[tt];
            const float du = dl * x1s[tt];
            #pragma unroll
            for (int n = 0; n < N; ++n) {
                const float dA = expf(dl * Aa[n]);
                h[n] = dA * h[n] + du * s_xdbl[tt][16 + n];
            }
        }
        if (l > 3) {
            const float dl = delta[3];
            const float du = dl * x1s[3];
            const float steps = (float)(l - 3);
            #pragma unroll
            for (int n = 0; n < N; ++n) {
                const float z   = dl * Aa[n];      // z < 0
                const float em1 = expm1f(z);
                const float emN = expm1f(steps * z);
                const float ratio = (em1 != 0.0f) ? (emN / em1) : steps;
                const float pw = emN + 1.0f;       // dA^steps
                h[n] = pw * h[n] + du * s_xdbl[3][16 + n] * ratio;
            }
        }
        const int fc = ((l - 1) < 3) ? (l - 1) : 3;
        float y = 0.0f;
        #pragma unroll
        for (int n = 0; n < N; ++n) y += h[n] * s_xdbl[fc][32 + n];
        y += x1s[fc] * Dp[j];
        const float res1 = ws[WS_RES1 + b * D + j];
        y *= silu_f(res1);
        ws[WS_Y + b * D + j] = y;
    }
}

// ---------------- K3: out_w matvec + final rmsnorm ----------------
// grid: 64 blocks, 1024 threads (256 dots x 4 threads/dot).
__global__ __launch_bounds__(1024) void k_out(
    const float* __restrict__ ws, const float* __restrict__ out_w,
    const float* __restrict__ norm_w, float* __restrict__ out)
{
    __shared__ float s_y[D];
    __shared__ float s_z[D];
    __shared__ float s_red[16];
    const int b = blockIdx.x;
    const int t = threadIdx.x;

    if (t < D) s_y[t] = ws[WS_Y + b * D + t];
    __syncthreads();

    const int o = t >> 2;
    const int q = t & 3;
    const float* __restrict__ orow = out_w + (size_t)o * D;
    float acc = 0.0f;
    #pragma unroll
    for (int k = 0; k < 16; ++k) {
        const int e = q * 4 + 16 * k;
        const float4 w4 = *(const float4*)(orow + e);
        const float4 y4 = *(const float4*)(s_y + e);
        acc += w4.x*y4.x + w4.y*y4.y + w4.z*y4.z + w4.w*y4.w;
    }
    acc += __shfl_xor(acc, 1, 64);
    acc += __shfl_xor(acc, 2, 64);
    if (q == 0) s_z[o] = acc;
    __syncthreads();

    const float zz = (t < D) ? s_z[t] : 0.0f;
    float p = zz * zz;
    #pragma unroll
    for (int off = 32; off >= 1; off >>= 1) p += __shfl_down(p, off, 64);
    if ((t & 63) == 0) s_red[t >> 6] = p;
    __syncthreads();
    if (t < D) {
        const float ss = s_red[0] + s_red[1] + s_red[2] + s_red[3];
        out[b * D + t] = zz * rsqrtf(ss * (1.0f / D) + 1e-5f) * norm_w[t];
    }
}

extern "C" void kernel_launch(void* const* d_in, const int* in_sizes, int n_in,
                              void* d_out, int out_size, void* d_ws, size_t ws_size,
                              hipStream_t stream) {
    const float* x1      = (const float*)d_in[0];
    const float* x2      = (const float*)d_in[1];
    const float* norm_w  = (const float*)d_in[2];
    const float* conv_w  = (const float*)d_in[3];
    const float* conv_b  = (const float*)d_in[4];
    const float* in_w    = (const float*)d_in[5];
    const float* xproj_w = (const float*)d_in[6];
    const float* dt_w    = (const float*)d_in[7];
    const float* dt_b    = (const float*)d_in[8];
    const float* out_w   = (const float*)d_in[9];
    const float* A_log   = (const float*)d_in[10];
    const float* Dp      = (const float*)d_in[11];
    const int*   l_ptr   = (const int*)d_in[12];
    float* out = (float*)d_out;
    float* ws  = (float*)d_ws;

    const int batch = in_sizes[0] / D;   // 64

    // K1: 12 blocks per batch (768 dots / 64 dots-per-block)
    k_inw<<<dim3(batch * 12), dim3(256), 0, stream>>>(x1, x2, norm_w, in_w, ws);
    // K2: one block per batch
    k_scan<<<dim3(batch), dim3(1024), 0, stream>>>(conv_w, conv_b, xproj_w,
                                                   dt_w, dt_b, A_log, Dp, l_ptr, ws);
    // K3: one block per batch
    k_out<<<dim3(batch), dim3(1024), 0, stream>>>(ws, out_w, norm_w, out);
}

// Round 3
// 95.425 us; speedup vs baseline: 1.1950x; 1.0160x over previous
//
#include <hip/hip_runtime.h>
#include <math.h>

#define D 256
#define N 16
#define R 16

// workspace float offsets (only 192 KB used)
#define WS_X1C  0
#define WS_RES1 16384
#define WS_X2C  32768

__device__ __forceinline__ float silu_f(float x) { return x / (1.0f + expf(-x)); }
__device__ __forceinline__ float softplus_f(float x) {
    return fmaxf(x, 0.0f) + log1pf(expf(-fabsf(x)));
}

// ---------------- K1: rmsnorm + in_w matvec ----------------
// grid: 768 blocks (12/batch), 256 threads. Block handles 64 dots.
//   o in [0,256):   x1c  = n1 . in_w[o]
//   o in [256,512): res1 = n1 . in_w[o]
//   o in [512,768): x2c  = n2 . in_w[o-512]
__global__ __launch_bounds__(256) void k_inw(
    const float* __restrict__ x1_in, const float* __restrict__ x2_in,
    const float* __restrict__ norm_w, const float* __restrict__ in_w,
    float* __restrict__ ws)
{
    __shared__ float s_n[D];
    __shared__ float s_red[4];
    const int t  = threadIdx.x;
    const int g0 = blockIdx.x * 64;
    const int b  = g0 / 768;
    const int o0 = g0 % 768;
    const bool use2 = (o0 >= 512);

    const float* __restrict__ xrow = (use2 ? x2_in : x1_in) + (size_t)b * D;
    const float v = xrow[t];
    float p = v * v;
    #pragma unroll
    for (int off = 32; off >= 1; off >>= 1) p += __shfl_down(p, off, 64);
    if ((t & 63) == 0) s_red[t >> 6] = p;
    __syncthreads();
    const float ss = s_red[0] + s_red[1] + s_red[2] + s_red[3];
    s_n[t] = v * rsqrtf(ss * (1.0f / D) + 1e-5f) * norm_w[t];
    __syncthreads();

    const int o   = o0 + (t >> 2);
    const int q   = t & 3;
    const int row = (o >= 512) ? (o - 512) : o;
    const float* __restrict__ wr = in_w + (size_t)row * D;
    float acc = 0.0f;
    #pragma unroll
    for (int k = 0; k < 16; ++k) {
        const int e = q * 4 + 16 * k;
        const float4 w4 = *(const float4*)(wr + e);
        const float4 n4 = *(const float4*)(s_n + e);
        acc += w4.x*n4.x + w4.y*n4.y + w4.z*n4.z + w4.w*n4.w;
    }
    acc += __shfl_xor(acc, 1, 64);
    acc += __shfl_xor(acc, 2, 64);
    if (q == 0) {
        const int jj = o & 255;
        float* dst = (o < 256) ? (ws + WS_X1C)
                   : (o < 512) ? (ws + WS_RES1)
                               : (ws + WS_X2C);
        dst[b * D + jj] = acc;
    }
}

// ---------------- K2: conv+silu, xproj, dt, scan, y, out_w, rmsnorm ----------
// grid: 64 blocks (one per batch), 1024 threads. Everything stays in LDS.
__global__ __launch_bounds__(1024) void k_fused(
    const float* __restrict__ conv_w, const float* __restrict__ conv_b,
    const float* __restrict__ xproj_w, const float* __restrict__ dt_w,
    const float* __restrict__ dt_b, const float* __restrict__ A_log,
    const float* __restrict__ Dp, const int* __restrict__ l_ptr,
    const float* __restrict__ out_w, const float* __restrict__ norm_w,
    const float* __restrict__ ws, float* __restrict__ out)
{
    __shared__ float s_x2s[4][D];
    __shared__ float s_xdbl[4][48];   // [tc][delta(16)|B(16)|C(16)]
    __shared__ float s_y[D];
    __shared__ float s_z[D];
    __shared__ float s_red[16];
    const int b = blockIdx.x;
    const int t = threadIdx.x;
    const int l = *l_ptr;

    // ---- phase A: conv + silu (threads 0..255) ----
    float x1s[4];
    float res1 = 0.0f;
    if (t < D) {
        const float x1c = ws[WS_X1C + b * D + t];
        const float x2c = ws[WS_X2C + b * D + t];
        res1 = ws[WS_RES1 + b * D + t];
        const float4 cw = *(const float4*)(conv_w + 4 * t);
        const float cb  = conv_b[t];
        float ksum[4];
        ksum[0] = cw.w;
        ksum[1] = cw.z + cw.w;
        ksum[2] = cw.y + cw.z + cw.w;
        ksum[3] = cw.x + cw.y + cw.z + cw.w;
        #pragma unroll
        for (int tc = 0; tc < 4; ++tc) {
            x1s[tc] = silu_f(ksum[tc] * x1c + cb);
            s_x2s[tc][t] = silu_f(ksum[tc] * x2c + cb);
        }
    }
    __syncthreads();

    // ---- phase B: xproj, 192 dots x 4 threads ----
    const int dotid = t >> 2;
    const int q     = t & 3;
    if (t < 768) {
        const int tc = dotid / 48;
        const int o  = dotid % 48;
        const float* __restrict__ pr = xproj_w + (size_t)o * D;
        const float* __restrict__ xs = s_x2s[tc];
        float acc = 0.0f;
        #pragma unroll
        for (int k = 0; k < 16; ++k) {
            const int e = q * 4 + 16 * k;
            const float4 p4 = *(const float4*)(pr + e);
            const float4 x4 = *(const float4*)(xs + e);
            acc += p4.x*x4.x + p4.y*x4.y + p4.z*x4.z + p4.w*x4.w;
        }
        acc += __shfl_xor(acc, 1, 64);
        acc += __shfl_xor(acc, 2, 64);
        if (q == 0) s_xdbl[tc][o] = acc;
    }
    __syncthreads();

    // ---- phase C: delta, scan, y (threads 0..255) ----
    if (t < D) {
        const int j = t;
        const float* __restrict__ dtrow = dt_w + (size_t)j * R;
        float dtr[R];
        #pragma unroll
        for (int qq = 0; qq < R; ++qq) dtr[qq] = dtrow[qq];
        const float dtb = dt_b[j];
        float delta[4];
        #pragma unroll
        for (int tc = 0; tc < 4; ++tc) {
            float acc = 0.0f;
            #pragma unroll
            for (int qq = 0; qq < R; ++qq) acc += s_xdbl[tc][qq] * dtr[qq];
            delta[tc] = softplus_f(acc + dtb);
        }
        const float* __restrict__ arow = A_log + (size_t)j * N;
        float Aa[N];
        #pragma unroll
        for (int n = 0; n < N; ++n) Aa[n] = -expf(arow[n]);
        float h[N];
        #pragma unroll
        for (int n = 0; n < N; ++n) h[n] = 0.0f;
        const int nexp = (l < 3) ? l : 3;
        for (int tt = 0; tt < nexp; ++tt) {
            const float dl = delta[tt];
            const float du = dl * x1s[tt];
            #pragma unroll
            for (int n = 0; n < N; ++n) {
                const float dA = expf(dl * Aa[n]);
                h[n] = dA * h[n] + du * s_xdbl[tt][16 + n];
            }
        }
        if (l > 3) {
            const float dl = delta[3];
            const float du = dl * x1s[3];
            const float steps = (float)(l - 3);
            #pragma unroll
            for (int n = 0; n < N; ++n) {
                const float z   = dl * Aa[n];      // z < 0
                const float em1 = expm1f(z);
                const float emN = expm1f(steps * z);
                const float ratio = (em1 != 0.0f) ? (emN / em1) : steps;
                const float pw = emN + 1.0f;       // dA^steps
                h[n] = pw * h[n] + du * s_xdbl[3][16 + n] * ratio;
            }
        }
        const int fc = ((l - 1) < 3) ? (l - 1) : 3;
        float y = 0.0f;
        #pragma unroll
        for (int n = 0; n < N; ++n) y += h[n] * s_xdbl[fc][32 + n];
        y += x1s[fc] * Dp[j];
        y *= silu_f(res1);
        s_y[j] = y;
    }
    __syncthreads();

    // ---- phase D: out_w matvec, 256 dots x 4 threads = all 1024 ----
    {
        const float* __restrict__ orow = out_w + (size_t)dotid * D;
        float acc = 0.0f;
        #pragma unroll
        for (int k = 0; k < 16; ++k) {
            const int e = q * 4 + 16 * k;
            const float4 w4 = *(const float4*)(orow + e);
            const float4 y4 = *(const float4*)(s_y + e);
            acc += w4.x*y4.x + w4.y*y4.y + w4.z*y4.z + w4.w*y4.w;
        }
        acc += __shfl_xor(acc, 1, 64);
        acc += __shfl_xor(acc, 2, 64);
        if (q == 0) s_z[dotid] = acc;
    }
    __syncthreads();

    // ---- final rmsnorm ----
    const float zz = (t < D) ? s_z[t] : 0.0f;
    float p = zz * zz;
    #pragma unroll
    for (int off = 32; off >= 1; off >>= 1) p += __shfl_down(p, off, 64);
    if ((t & 63) == 0) s_red[t >> 6] = p;
    __syncthreads();
    if (t < D) {
        const float ss = s_red[0] + s_red[1] + s_red[2] + s_red[3];
        out[b * D + t] = zz * rsqrtf(ss * (1.0f / D) + 1e-5f) * norm_w[t];
    }
}

extern "C" void kernel_launch(void* const* d_in, const int* in_sizes, int n_in,
                              void* d_out, int out_size, void* d_ws, size_t ws_size,
                              hipStream_t stream) {
    const float* x1      = (const float*)d_in[0];
    const float* x2      = (const float*)d_in[1];
    const float* norm_w  = (const float*)d_in[2];
    const float* conv_w  = (const float*)d_in[3];
    const float* conv_b  = (const float*)d_in[4];
    const float* in_w    = (const float*)d_in[5];
    const float* xproj_w = (const float*)d_in[6];
    const float* dt_w    = (const float*)d_in[7];
    const float* dt_b    = (const float*)d_in[8];
    const float* out_w   = (const float*)d_in[9];
    const float* A_log   = (const float*)d_in[10];
    const float* Dp      = (const float*)d_in[11];
    const int*   l_ptr   = (const int*)d_in[12];
    float* out = (float*)d_out;
    float* ws  = (float*)d_ws;

    const int batch = in_sizes[0] / D;   // 64

    k_inw<<<dim3(batch * 12), dim3(256), 0, stream>>>(x1, x2, norm_w, in_w, ws);
    k_fused<<<dim3(batch), dim3(1024), 0, stream>>>(conv_w, conv_b, xproj_w,
                                                    dt_w, dt_b, A_log, Dp, l_ptr,
                                                    out_w, norm_w, ws, out);
}